// Round 3
// baseline (125.817 us; speedup 1.0000x reference)
//
#include <hip/hip_runtime.h>
#include <math.h>

#define M_BATCH 8
#define NC 1024
#define NT 512
#define S_SPLIT 4
#define KSLICE (NC / S_SPLIT)      // 256 ctx per block
#define KCHUNK 128                 // ctx staged per LDS chunk
#define NCHUNK (KSLICE / KCHUNK)   // 2
#define TS 32                      // grid cells per dim per block

#if defined(__has_builtin)
#if __has_builtin(__builtin_amdgcn_exp2f)
#define FAST_EXP2(x) __builtin_amdgcn_exp2f(x)
#endif
#endif
#ifndef FAST_EXP2
#define FAST_EXP2(x) exp2f(x)
#endif

// Pre-kernel: per-m min/max over concat(xc, xt) -> x_mid (M,2) in ws.
__global__ __launch_bounds__(256) void minmax_kernel(
        const float* __restrict__ xc, const float* __restrict__ xt,
        float* __restrict__ xmid) {
    const int m = blockIdx.x;
    const int tid = threadIdx.x;
    float mn0 = 1e30f, mx0 = -1e30f, mn1 = 1e30f, mx1 = -1e30f;
    const float2* pc = (const float2*)(xc + m * NC * 2);
    for (int i = tid; i < NC; i += 256) {
        float2 p = pc[i];
        mn0 = fminf(mn0, p.x); mx0 = fmaxf(mx0, p.x);
        mn1 = fminf(mn1, p.y); mx1 = fmaxf(mx1, p.y);
    }
    const float2* pt = (const float2*)(xt + m * NT * 2);
    for (int i = tid; i < NT; i += 256) {
        float2 p = pt[i];
        mn0 = fminf(mn0, p.x); mx0 = fmaxf(mx0, p.x);
        mn1 = fminf(mn1, p.y); mx1 = fmaxf(mx1, p.y);
    }
    __shared__ float4 sm[256];
    sm[tid] = make_float4(mn0, mx0, mn1, mx1);
    __syncthreads();
    for (int s = 128; s > 0; s >>= 1) {
        if (tid < s) {
            float4 a = sm[tid], b = sm[tid + s];
            sm[tid] = make_float4(fminf(a.x, b.x), fmaxf(a.y, b.y),
                                  fminf(a.z, b.z), fmaxf(a.w, b.w));
        }
        __syncthreads();
    }
    if (tid == 0) {
        xmid[m * 2 + 0] = 0.5f * (sm[0].x + sm[0].y);
        xmid[m * 2 + 1] = 0.5f * (sm[0].z + sm[0].w);
    }
}

// Main kernel: separable weights. Block = (tile(tx,ty), kslice s, m).
// Stage wx[c][i], wy[c][j], y[c] in LDS; inner loop is pure mul/fma.
__global__ __launch_bounds__(256) void setconv_main(
        const float* __restrict__ xc, const float* __restrict__ yc,
        const float* __restrict__ lsp, const float* __restrict__ xmid,
        float* __restrict__ out_grid,   // (M, ng, 2)
        float* __restrict__ out_z,      // (M, ng, 3)
        int G, int ng, int tpd) {
    const int tid = threadIdx.x;
    const int m = blockIdx.z;
    const int s = blockIdx.y;
    const int tx = blockIdx.x / tpd;
    const int ty = blockIdx.x - tx * tpd;

    __shared__ float wxs[KCHUNK * TS];
    __shared__ float wys[KCHUNK * TS];
    __shared__ float2 ysm[KCHUNK];

    // w = exp(-0.5*((dx/ls0)^2+(dy/ls1)^2)) = exp2(-((K*dx/ls0)^2+(K*dy/ls1)^2))
    const float Kc = 0.84932180028801904272f;  // sqrt(0.5*log2(e))
    const float ls0 = 1e-5f + log1pf(expf(lsp[0]));
    const float ls1 = 1e-5f + log1pf(expf(lsp[1]));
    const float s0 = Kc / ls0, s1 = Kc / ls1;

    const float mid0 = xmid[m * 2 + 0];
    const float mid1 = xmid[m * 2 + 1];
    const float half = (float)((G - 1) >> 1);
    const float inv_ppu = 1.0f / 64.0f;

    const float* xcm = xc + m * NC * 2;
    const float2* ycm = (const float2*)(yc + m * NC * 2);

    const int tix = tid >> 4;       // 0..15
    const int tiy = tid & 15;       // 0..15
    const int gix0 = tx * TS + 2 * tix;
    const int giy0 = ty * TS + 2 * tiy;
    const bool active = (gix0 < G) && (giy0 < G);

    float acc[2][2][3];
#pragma unroll
    for (int a = 0; a < 2; ++a)
#pragma unroll
        for (int b = 0; b < 2; ++b)
#pragma unroll
            for (int ch = 0; ch < 3; ++ch) acc[a][b][ch] = 0.0f;

    for (int k = 0; k < NCHUNK; ++k) {
        const int cb = s * KSLICE + k * KCHUNK;
        // stage wx, wy (KCHUNK x TS each) and y (KCHUNK)
        for (int idx = tid; idx < KCHUNK * TS; idx += 256) {
            const int c = idx >> 5;       // TS == 32
            const int i = idx & 31;
            const float cx = xcm[2 * (cb + c) + 0];
            const float cy = xcm[2 * (cb + c) + 1];
            // grid coord (ref op order), then scale
            const float gx = mid0 + (float)(tx * TS + i - (G - 1) / 2) * inv_ppu;
            const float gy = mid1 + (float)(ty * TS + i - (G - 1) / 2) * inv_ppu;
            const float dx = fmaf(-cx, s0, gx * s0);
            const float dy = fmaf(-cy, s1, gy * s1);
            wxs[idx] = FAST_EXP2(-(dx * dx));
            wys[idx] = FAST_EXP2(-(dy * dy));
        }
        if (tid < KCHUNK) ysm[tid] = ycm[cb + tid];
        __syncthreads();

        if (active) {
#pragma unroll 4
            for (int c = 0; c < KCHUNK; ++c) {
                const float2 wxp = *(const float2*)&wxs[c * TS + 2 * tix];
                const float2 wyp = *(const float2*)&wys[c * TS + 2 * tiy];
                const float2 yv = ysm[c];
                const float t00 = wxp.x * wyp.x;
                const float t01 = wxp.x * wyp.y;
                const float t10 = wxp.y * wyp.x;
                const float t11 = wxp.y * wyp.y;
                acc[0][0][0] = fmaf(t00, yv.x, acc[0][0][0]);
                acc[0][0][1] = fmaf(t00, yv.y, acc[0][0][1]);
                acc[0][0][2] += t00;
                acc[0][1][0] = fmaf(t01, yv.x, acc[0][1][0]);
                acc[0][1][1] = fmaf(t01, yv.y, acc[0][1][1]);
                acc[0][1][2] += t01;
                acc[1][0][0] = fmaf(t10, yv.x, acc[1][0][0]);
                acc[1][0][1] = fmaf(t10, yv.y, acc[1][0][1]);
                acc[1][0][2] += t10;
                acc[1][1][0] = fmaf(t11, yv.x, acc[1][1][0]);
                acc[1][1][1] = fmaf(t11, yv.y, acc[1][1][1]);
                acc[1][1][2] += t11;
            }
        }
        __syncthreads();
    }

    if (active) {
#pragma unroll
        for (int a = 0; a < 2; ++a) {
            const int gix = gix0 + a;
            if (gix >= G) continue;
#pragma unroll
            for (int b = 0; b < 2; ++b) {
                const int giy = giy0 + b;
                if (giy >= G) continue;
                const size_t g = (size_t)m * ng + (size_t)gix * G + giy;
                if (s == 0) {
                    const float gx = mid0 + (float)(gix - (G - 1) / 2) * inv_ppu;
                    const float gy = mid1 + (float)(giy - (G - 1) / 2) * inv_ppu;
                    float2* og = (float2*)(out_grid + 2 * g);
                    *og = make_float2(gx, gy);
                }
                float* oz = out_z + 3 * g;
                __hip_atomic_fetch_add(oz + 0, acc[a][b][0], __ATOMIC_RELAXED, __HIP_MEMORY_SCOPE_AGENT);
                __hip_atomic_fetch_add(oz + 1, acc[a][b][1], __ATOMIC_RELAXED, __HIP_MEMORY_SCOPE_AGENT);
                __hip_atomic_fetch_add(oz + 2, acc[a][b][2], __ATOMIC_RELAXED, __HIP_MEMORY_SCOPE_AGENT);
            }
        }
    }
}

extern "C" void kernel_launch(void* const* d_in, const int* in_sizes, int n_in,
                              void* d_out, int out_size, void* d_ws, size_t ws_size,
                              hipStream_t stream) {
    const float* xc  = (const float*)d_in[0];
    const float* yc  = (const float*)d_in[1];
    const float* xt  = (const float*)d_in[2];
    const float* lsp = (const float*)d_in[3];

    // out = x_grid (M*ng*2) ++ z_grid (M*ng*3)  =>  ng = out_size / (5*M)
    const int ng = out_size / (5 * M_BATCH);
    const int G = (int)(sqrt((double)ng) + 0.5);  // 129
    const int tpd = (G + TS - 1) / TS;            // 5

    float* xmid = (float*)d_ws;  // (M,2) floats
    float* out_grid = (float*)d_out;
    float* out_z = out_grid + (size_t)M_BATCH * ng * 2;

    hipMemsetAsync(out_z, 0, (size_t)M_BATCH * ng * 3 * sizeof(float), stream);
    minmax_kernel<<<M_BATCH, 256, 0, stream>>>(xc, xt, xmid);

    dim3 grid(tpd * tpd, S_SPLIT, M_BATCH);
    setconv_main<<<grid, 256, 0, stream>>>(xc, yc, lsp, xmid, out_grid, out_z, G, ng, tpd);
}

// Round 4
// 97.435 us; speedup vs baseline: 1.2913x; 1.2913x over previous
//
#include <hip/hip_runtime.h>
#include <math.h>

#define M_BATCH 8
#define NC 1024
#define NT 512
#define KCHUNK 128                 // ctx staged per LDS chunk
#define TS 32                      // grid cells per dim per block

#if defined(__has_builtin)
#if __has_builtin(__builtin_amdgcn_exp2f)
#define FAST_EXP2(x) __builtin_amdgcn_exp2f(x)
#endif
#endif
#ifndef FAST_EXP2
#define FAST_EXP2(x) exp2f(x)
#endif

// Pre-kernel: per-m min/max over concat(xc, xt) -> x_mid (M,2) in ws.
__global__ __launch_bounds__(256) void minmax_kernel(
        const float* __restrict__ xc, const float* __restrict__ xt,
        float* __restrict__ xmid) {
    const int m = blockIdx.x;
    const int tid = threadIdx.x;
    float mn0 = 1e30f, mx0 = -1e30f, mn1 = 1e30f, mx1 = -1e30f;
    const float2* pc = (const float2*)(xc + m * NC * 2);
    for (int i = tid; i < NC; i += 256) {
        float2 p = pc[i];
        mn0 = fminf(mn0, p.x); mx0 = fmaxf(mx0, p.x);
        mn1 = fminf(mn1, p.y); mx1 = fmaxf(mx1, p.y);
    }
    const float2* pt = (const float2*)(xt + m * NT * 2);
    for (int i = tid; i < NT; i += 256) {
        float2 p = pt[i];
        mn0 = fminf(mn0, p.x); mx0 = fmaxf(mx0, p.x);
        mn1 = fminf(mn1, p.y); mx1 = fmaxf(mx1, p.y);
    }
    __shared__ float4 sm[256];
    sm[tid] = make_float4(mn0, mx0, mn1, mx1);
    __syncthreads();
    for (int s = 128; s > 0; s >>= 1) {
        if (tid < s) {
            float4 a = sm[tid], b = sm[tid + s];
            sm[tid] = make_float4(fminf(a.x, b.x), fmaxf(a.y, b.y),
                                  fminf(a.z, b.z), fmaxf(a.w, b.w));
        }
        __syncthreads();
    }
    if (tid == 0) {
        xmid[m * 2 + 0] = 0.5f * (sm[0].x + sm[0].y);
        xmid[m * 2 + 1] = 0.5f * (sm[0].z + sm[0].w);
    }
}

// Main kernel: separable weights, K-split partials to ws (plain stores, no
// atomics). Block = (tile(tx,ty), kslice s, m). Thread = 2x2 cells.
__global__ __launch_bounds__(256, 4) void setconv_main(
        const float* __restrict__ xc, const float* __restrict__ yc,
        const float* __restrict__ lsp, const float* __restrict__ xmid,
        float* __restrict__ out_grid,   // (M, ng, 2)
        float* __restrict__ pz,         // (S, M, ng, 3) partials
        int G, int ng, int tpd, int nchunk) {
    const int tid = threadIdx.x;
    const int m = blockIdx.z;
    const int s = blockIdx.y;
    const int tx = blockIdx.x / tpd;
    const int ty = blockIdx.x - tx * tpd;

    __shared__ float wxs[KCHUNK * TS];
    __shared__ float wys[KCHUNK * TS];
    __shared__ float2 ysm[KCHUNK];

    // w = exp(-0.5*((dx/ls0)^2+(dy/ls1)^2)) = exp2(-((K*dx/ls0)^2+(K*dy/ls1)^2))
    const float Kc = 0.84932180028801904272f;  // sqrt(0.5*log2(e))
    const float ls0 = 1e-5f + log1pf(expf(lsp[0]));
    const float ls1 = 1e-5f + log1pf(expf(lsp[1]));
    const float s0 = Kc / ls0, s1 = Kc / ls1;

    const float mid0 = xmid[m * 2 + 0];
    const float mid1 = xmid[m * 2 + 1];
    const float inv_ppu = 1.0f / 64.0f;
    const int halfg = (G - 1) >> 1;

    const float* xcm = xc + m * NC * 2;
    const float2* ycm = (const float2*)(yc + m * NC * 2);

    const int tix = tid >> 4;       // 0..15
    const int tiy = tid & 15;       // 0..15
    const int gix0 = tx * TS + 2 * tix;
    const int giy0 = ty * TS + 2 * tiy;
    const bool active = (gix0 < G) && (giy0 < G);

    float acc[2][2][3];
#pragma unroll
    for (int a = 0; a < 2; ++a)
#pragma unroll
        for (int b = 0; b < 2; ++b)
#pragma unroll
            for (int ch = 0; ch < 3; ++ch) acc[a][b][ch] = 0.0f;

    const int kbase = s * (nchunk * KCHUNK);
    for (int k = 0; k < nchunk; ++k) {
        const int cb = kbase + k * KCHUNK;
        // stage wx, wy (KCHUNK x TS each) and y (KCHUNK)
        for (int idx = tid; idx < KCHUNK * TS; idx += 256) {
            const int c = idx >> 5;       // TS == 32
            const int i = idx & 31;
            const float cx = xcm[2 * (cb + c) + 0];
            const float cy = xcm[2 * (cb + c) + 1];
            const float gx = mid0 + (float)(tx * TS + i - halfg) * inv_ppu;
            const float gy = mid1 + (float)(ty * TS + i - halfg) * inv_ppu;
            const float dx = fmaf(-cx, s0, gx * s0);
            const float dy = fmaf(-cy, s1, gy * s1);
            wxs[idx] = FAST_EXP2(-(dx * dx));
            wys[idx] = FAST_EXP2(-(dy * dy));
        }
        if (tid < KCHUNK) ysm[tid] = ycm[cb + tid];
        __syncthreads();

        if (active) {
#pragma unroll 4
            for (int c = 0; c < KCHUNK; ++c) {
                const float2 wxp = *(const float2*)&wxs[c * TS + 2 * tix];
                const float2 wyp = *(const float2*)&wys[c * TS + 2 * tiy];
                const float2 yv = ysm[c];
                const float t00 = wxp.x * wyp.x;
                const float t01 = wxp.x * wyp.y;
                const float t10 = wxp.y * wyp.x;
                const float t11 = wxp.y * wyp.y;
                acc[0][0][0] = fmaf(t00, yv.x, acc[0][0][0]);
                acc[0][0][1] = fmaf(t00, yv.y, acc[0][0][1]);
                acc[0][0][2] += t00;
                acc[0][1][0] = fmaf(t01, yv.x, acc[0][1][0]);
                acc[0][1][1] = fmaf(t01, yv.y, acc[0][1][1]);
                acc[0][1][2] += t01;
                acc[1][0][0] = fmaf(t10, yv.x, acc[1][0][0]);
                acc[1][0][1] = fmaf(t10, yv.y, acc[1][0][1]);
                acc[1][0][2] += t10;
                acc[1][1][0] = fmaf(t11, yv.x, acc[1][1][0]);
                acc[1][1][1] = fmaf(t11, yv.y, acc[1][1][1]);
                acc[1][1][2] += t11;
            }
        }
        __syncthreads();
    }

    if (active) {
        float* pzs = pz + (size_t)s * M_BATCH * ng * 3;
#pragma unroll
        for (int a = 0; a < 2; ++a) {
            const int gix = gix0 + a;
            if (gix >= G) continue;
#pragma unroll
            for (int b = 0; b < 2; ++b) {
                const int giy = giy0 + b;
                if (giy >= G) continue;
                const size_t g = (size_t)m * ng + (size_t)gix * G + giy;
                if (s == 0) {
                    const float gx = mid0 + (float)(gix - halfg) * inv_ppu;
                    const float gy = mid1 + (float)(giy - halfg) * inv_ppu;
                    float2* og = (float2*)(out_grid + 2 * g);
                    *og = make_float2(gx, gy);
                }
                float* oz = pzs + 3 * g;
                oz[0] = acc[a][b][0];
                oz[1] = acc[a][b][1];
                oz[2] = acc[a][b][2];
            }
        }
    }
}

// Flat elementwise reduce: out_z[i] = sum_s pz[s][i]. Layout-agnostic.
__global__ __launch_bounds__(256) void reduce_kernel(
        const float4* __restrict__ pz, float4* __restrict__ out_z,
        int nq, int S) {
    const int i = blockIdx.x * 256 + threadIdx.x;
    if (i >= nq) return;
    float4 o = pz[i];
    for (int s = 1; s < S; ++s) {
        float4 p = pz[(size_t)s * nq + i];
        o.x += p.x; o.y += p.y; o.z += p.z; o.w += p.w;
    }
    out_z[i] = o;
}

extern "C" void kernel_launch(void* const* d_in, const int* in_sizes, int n_in,
                              void* d_out, int out_size, void* d_ws, size_t ws_size,
                              hipStream_t stream) {
    const float* xc  = (const float*)d_in[0];
    const float* yc  = (const float*)d_in[1];
    const float* xt  = (const float*)d_in[2];
    const float* lsp = (const float*)d_in[3];

    // out = x_grid (M*ng*2) ++ z_grid (M*ng*3)  =>  ng = out_size / (5*M)
    const int ng = out_size / (5 * M_BATCH);
    const int G = (int)(sqrt((double)ng) + 0.5);  // 129
    const int tpd = (G + TS - 1) / TS;            // 5

    float* xmid = (float*)d_ws;                   // (M,2) floats, 64B slot
    float* pz = (float*)((char*)d_ws + 64);
    float* out_grid = (float*)d_out;
    float* out_z = out_grid + (size_t)M_BATCH * ng * 2;

    // pick largest K-split S (power of 2, <=8) whose partials fit in ws
    const size_t zbytes = (size_t)M_BATCH * ng * 3 * sizeof(float);
    int S = 8;
    while (S > 1 && 64 + (size_t)S * zbytes > ws_size) S >>= 1;
    const int nchunk = NC / (S * KCHUNK);         // 1 for S=8

    minmax_kernel<<<M_BATCH, 256, 0, stream>>>(xc, xt, xmid);

    dim3 grid(tpd * tpd, S, M_BATCH);
    setconv_main<<<grid, 256, 0, stream>>>(xc, yc, lsp, xmid, out_grid, pz,
                                           G, ng, tpd, nchunk);

    const int nq = (M_BATCH * ng * 3) / 4;        // divisible: 399384/4
    reduce_kernel<<<(nq + 255) / 256, 256, 0, stream>>>(
        (const float4*)pz, (float4*)out_z, nq, S);
}